// Round 2
// baseline (603.682 us; speedup 1.0000x reference)
//
#include <hip/hip_runtime.h>
#include <cstdint>
#include <cstddef>

// LoRALinear: out[T,M] = x[T,N] @ (W + A@B^T)^T + b   (alpha = 8/8 = 1)
// T=8192, M=4096, N=4096, RANK=8, fp32 in/out.
//
// Round-5 (vs round-4):
//  * MFMA 16x16x32 -> 32x32x16 (ceiling 2075 -> 2495 TF, -17% matrix cycles,
//    same LDS traffic, same register budget).
//  * 8 phases/iter (2 barriers each) -> 4 phases/iter (ONE barrier each).
//    Phase = {4x global_load_lds stage, 8-16x ds_read_b128, 16x MFMA, BAR}.
//    Hazard discipline: a stage in phase k only overwrites LDS rows whose
//    last ds_reads were issued in phase k-1 (drained by that phase's
//    lgkmcnt before its MMA, hence globally complete at its end barrier).
//    Fresh-staged buffers are only read after a vmcnt(4)+BAR checkpoint.
//  * vmcnt(4) twice per iter; the loads it waits on were issued one full
//    phase (~1000 cyc) earlier.

#define T_DIM 8192
#define M_DIM 4096
#define N_DIM 4096
#define RANK  8

typedef _Float16 f16x8  __attribute__((ext_vector_type(8)));
typedef float    f32x4  __attribute__((ext_vector_type(4)));
typedef float    f32x16 __attribute__((ext_vector_type(16)));

// ---------------------------------------------------------------- pass 1
// pure fp32 -> f16 streaming cast (x)
__global__ __launch_bounds__(256)
void cast_x(const float* __restrict__ src, _Float16* __restrict__ dst) {
    size_t i = ((size_t)blockIdx.x * blockDim.x + threadIdx.x) * 8;
    f32x4 v0 = *(const f32x4*)(src + i);
    f32x4 v1 = *(const f32x4*)(src + i + 4);
    f16x8 o;
#pragma unroll
    for (int k = 0; k < 4; ++k) { o[k] = (_Float16)v0[k]; o[4 + k] = (_Float16)v1[k]; }
    *(f16x8*)(dst + i) = o;
}

// ---------------------------------------------------------------- pass 2
// Wh[m][n] = f16( W[m][n] + dot(A[m,:], B[n,:]) )
__global__ __launch_bounds__(256)
void prep_w(const float* __restrict__ W, const float* __restrict__ A,
            const float* __restrict__ B, _Float16* __restrict__ Wh) {
    const size_t c = (size_t)blockIdx.x * 256 + threadIdx.x;
    const int m  = (int)(c >> 9);
    const int n0 = (int)(c & 511) << 3;
    f32x4 a0 = *(const f32x4*)(A + (size_t)m * RANK);
    f32x4 a1 = *(const f32x4*)(A + (size_t)m * RANK + 4);
    const float* wp = W + (size_t)m * N_DIM + n0;
    f32x4 w0 = *(const f32x4*)wp;
    f32x4 w1 = *(const f32x4*)(wp + 4);
    f16x8 o;
#pragma unroll
    for (int k = 0; k < 8; ++k) {
        const float* Bn = B + (size_t)(n0 + k) * RANK;
        f32x4 b0 = *(const f32x4*)Bn;
        f32x4 b1 = *(const f32x4*)(Bn + 4);
        float d = a0[0]*b0[0] + a0[1]*b0[1] + a0[2]*b0[2] + a0[3]*b0[3]
                + a1[0]*b1[0] + a1[1]*b1[1] + a1[2]*b1[2] + a1[3]*b1[3];
        float wv = (k < 4) ? w0[k] : w1[k - 4];
        o[k] = (_Float16)(wv + d);
    }
    *(f16x8*)(Wh + (size_t)m * N_DIM + n0) = o;
}

// ---------------------------------------------------------------- GEMM
__device__ static inline void gld16(const _Float16* g, _Float16* l) {
    __builtin_amdgcn_global_load_lds(
        (const __attribute__((address_space(1))) unsigned int*)g,
        (__attribute__((address_space(3))) unsigned int*)l, 16, 0, 0);
}

// 256x256 tile, BK=64, 512 threads = 8 waves (2M x 4N), per-wave C = 128x64
// as 4x2 tiles of 32x32, K split in 4 ksteps of 16.
// LDS: double-buffered [256][64] f16 for A and B = 128 KiB.
// 16B chunk c of row R stored at phys chunk c ^ (R&7) (involution; staged
// via pre-swizzled global source so global_load_lds' linear dest works).
// B rows permuted: phys p = nb*128 + wcn*32 + s <-> W row wcn*64 + nb*32 + s.
__global__ __launch_bounds__(512, 2)
void gemm256(const _Float16* __restrict__ Xh, const _Float16* __restrict__ Wh,
             const float* __restrict__ bias, float* __restrict__ out) {
    __shared__ __align__(16) _Float16 lA[2][256 * 64];
    __shared__ __align__(16) _Float16 lB[2][256 * 64];

    const int tid  = threadIdx.x;
    const int lane = tid & 63;
    const int l32  = lane & 31;
    const int lhi  = lane >> 5;
    const int w    = tid >> 6;
    const int wr   = w >> 2;      // 0..1  (M)
    const int wcn  = w & 3;       // 0..3  (N)

    const size_t rowX0 = (size_t)blockIdx.y * 256;
    const size_t rowW0 = (size_t)blockIdx.x * 256;

    // staging source addressing (per-thread, kt-invariant)
    const int srow = tid >> 3;                                // 0..63
    const int scol = ((tid & 7) * 8) ^ ((srow & 7) * 8);      // pre-swizzled col
    const _Float16* sA = Xh + (rowX0 + srow) * N_DIM + scol;
    const _Float16* sBp[4];
#pragma unroll
    for (int cb = 0; cb < 4; ++cb) {
        const int p = cb * 64 + srow;
        const int wrow = ((p >> 5) & 3) * 64 + ((p >> 7) & 1) * 32 + (p & 31);
        sBp[cb] = Wh + (rowW0 + wrow) * N_DIM + scol;
    }

    // fragment-read addressing: row + XOR-swizzled 16B chunk
    int rowA[4], rowB[2], chk[4];
#pragma unroll
    for (int mb = 0; mb < 4; ++mb) rowA[mb] = (wr * 128 + mb * 32 + l32) * 64;
#pragma unroll
    for (int nb = 0; nb < 2; ++nb) rowB[nb] = (nb * 128 + wcn * 32 + l32) * 64;
#pragma unroll
    for (int ks = 0; ks < 4; ++ks) chk[ks] = ((ks * 2 + lhi) ^ (lane & 7)) * 8;

    f32x16 acc[4][2] = {};
    f16x8  af[2][4], bf[2][4];

#define STAGE_A(b, rb, kt) gld16(sA + (size_t)(rb) * N_DIM + (kt) * 64, \
                                 &lA[b][(rb) * 64 + tid * 8])
#define STAGE_B(b, cb, kt) gld16(sBp[cb] + (size_t)(kt) * 64, \
                                 &lB[b][(cb) * 4096 + tid * 8])

#define LDAF(b, mbase) do { _Pragma("unroll") \
    for (int mm = 0; mm < 2; ++mm) { _Pragma("unroll") \
    for (int ks = 0; ks < 4; ++ks) \
        af[mm][ks] = *(const f16x8*)&lA[b][rowA[(mbase) + mm] + chk[ks]]; } } while (0)

#define LDBF(b) do { _Pragma("unroll") \
    for (int nb = 0; nb < 2; ++nb) { _Pragma("unroll") \
    for (int ks = 0; ks < 4; ++ks) \
        bf[nb][ks] = *(const f16x8*)&lB[b][rowB[nb] + chk[ks]]; } } while (0)

#define MMA(mbase) do { __builtin_amdgcn_s_setprio(1); \
    _Pragma("unroll") for (int mm = 0; mm < 2; ++mm) \
    _Pragma("unroll") for (int nb = 0; nb < 2; ++nb) \
    _Pragma("unroll") for (int ks = 0; ks < 4; ++ks) \
        acc[(mbase) + mm][nb] = __builtin_amdgcn_mfma_f32_32x32x16_f16( \
            af[mm][ks], bf[nb][ks], acc[(mbase) + mm][nb], 0, 0, 0); \
    __builtin_amdgcn_s_setprio(0); \
    __builtin_amdgcn_sched_barrier(0); } while (0)

#define BAR asm volatile("s_barrier" ::: "memory")
#define VW4 asm volatile("s_waitcnt vmcnt(4)" ::: "memory")
#define VW0 asm volatile("s_waitcnt vmcnt(0)" ::: "memory")

    // ---- prologue: kt0 full -> buf0 (8); kt1 A-q0 + B-h0 -> buf1 (4)
    STAGE_A(0, 0, 0);  STAGE_A(0, 64, 0);  STAGE_A(0, 128, 0);  STAGE_A(0, 192, 0);
    STAGE_B(0, 0, 0);  STAGE_B(0, 1, 0);   STAGE_B(0, 2, 0);    STAGE_B(0, 3, 0);
    STAGE_A(1, 0, 1);  STAGE_A(1, 128, 1); STAGE_B(1, 0, 1);    STAGE_B(1, 1, 1);
    VW4; BAR;   // kt0 confirmed; kt1-first(4) outstanding

    // ---- main loop: iter n computes kt 2n (buf0), 2n+1 (buf1)
#pragma unroll 1
    for (int n = 0; n < 31; ++n) {
        const int ko  = 2 * n + 1;
        const int ke2 = 2 * n + 2;
        const int ko2 = 2 * n + 3;
        // ph0: reads buf0 mb01+bf (rows A{0-63,128-191}, B all)
        STAGE_A(1, 64, ko); STAGE_A(1, 192, ko); STAGE_B(1, 2, ko); STAGE_B(1, 3, ko);
        LDBF(0); LDAF(0, 0); MMA(0); BAR;
        // ph1: reads buf0 mb23 (rows A{64-127,192-255}); stages overwrite
        // buf0 A{0-63,128-191}+B{0-127} (last read ph0)
        STAGE_A(0, 0, ke2); STAGE_A(0, 128, ke2); STAGE_B(0, 0, ke2); STAGE_B(0, 1, ke2);
        LDAF(0, 2); MMA(2); VW4; BAR;   // kt_odd confirmed (8 oldest done)
        // ph2: reads buf1 mb01+bf; stages overwrite buf0 A{64-127,192-255}
        // +B{128-255} (last read ph1/ph0)
        STAGE_A(0, 64, ke2); STAGE_A(0, 192, ke2); STAGE_B(0, 2, ke2); STAGE_B(0, 3, ke2);
        LDBF(1); LDAF(1, 0); MMA(0); BAR;
        // ph3: reads buf1 mb23; stages overwrite buf1 A{0-63,128-191}
        // +B{0-127} (last read ph2)
        STAGE_A(1, 0, ko2); STAGE_A(1, 128, ko2); STAGE_B(1, 0, ko2); STAGE_B(1, 1, ko2);
        LDAF(1, 2); MMA(2); VW4; BAR;   // kt_even+2 confirmed
    }

    // ---- final: kt62 (buf0), kt63 (buf1); no further prefetch
    STAGE_A(1, 64, 63); STAGE_A(1, 192, 63); STAGE_B(1, 2, 63); STAGE_B(1, 3, 63);
    LDBF(0); LDAF(0, 0); MMA(0); BAR;
    LDAF(0, 2); MMA(2); VW0; BAR;       // kt63 fully confirmed
    LDBF(1); LDAF(1, 0); MMA(0);
    LDAF(1, 2); MMA(2);

    // ---- epilogue: 32x32 C/D: col = l32, row = (r&3) + 8*(r>>2) + 4*lhi
    const int crow0 = (int)rowX0 + wr * 128;
    const int ccol0 = (int)rowW0 + wcn * 64;
    float bv[2];
#pragma unroll
    for (int nb = 0; nb < 2; ++nb) bv[nb] = bias[ccol0 + nb * 32 + l32];
#pragma unroll
    for (int mb = 0; mb < 4; ++mb) {
#pragma unroll
        for (int nb = 0; nb < 2; ++nb) {
#pragma unroll
            for (int r = 0; r < 16; ++r) {
                const size_t row = (size_t)(crow0 + mb * 32 + (r & 3) + 8 * (r >> 2) + 4 * lhi);
                out[row * M_DIM + ccol0 + nb * 32 + l32] = acc[mb][nb][r] + bv[nb];
            }
        }
    }
#undef STAGE_A
#undef STAGE_B
#undef LDAF
#undef LDBF
#undef MMA
#undef BAR
#undef VW4
#undef VW0
}

// ---------------------------------------------------------------- launch
extern "C" void kernel_launch(void* const* d_in, const int* in_sizes, int n_in,
                              void* d_out, int out_size, void* d_ws, size_t ws_size,
                              hipStream_t stream) {
    const float* x = (const float*)d_in[0];
    const float* W = (const float*)d_in[1];
    const float* b = (const float*)d_in[2];
    const float* A = (const float*)d_in[3];
    const float* B = (const float*)d_in[4];
    float* out = (float*)d_out;

    _Float16* Wh = (_Float16*)d_ws;
    _Float16* Xh = (_Float16*)((char*)d_ws + (size_t)M_DIM * N_DIM * 2);

    cast_x<<<((size_t)T_DIM * N_DIM / 8) / 256, 256, 0, stream>>>(x, Xh);
    prep_w<<<((size_t)M_DIM * N_DIM / 8) / 256, 256, 0, stream>>>(W, A, B, Wh);

    dim3 grid(M_DIM / 256, T_DIM / 256);
    gemm256<<<grid, dim3(512, 1, 1), 0, stream>>>(Xh, Wh, b, out);
}

// Round 3
// 575.275 us; speedup vs baseline: 1.0494x; 1.0494x over previous
//
#include <hip/hip_runtime.h>
#include <cstdint>
#include <cstddef>

// LoRALinear: out[T,M] = x[T,N] @ (W + A@B^T)^T + b   (alpha = 8/8 = 1)
// T=8192, M=4096, N=4096, RANK=8, fp32 in/out.
//
// Round-6 (revert round-5's 32x32 experiment; base = round-4 structure):
//  * Keep 16x16x32 MFMA + the exact round-4 fragment-read swizzle (proven
//    ZERO bank conflicts at 270us).
//  * Merge barrier pairs: 8 phases x 2 barriers -> 4 phases x 1 barrier
//    per iter (16 -> 4 barriers). Safe because each wave's ds_reads are
//    consumed by its own MFMAs before it reaches the phase-end barrier, so
//    the end barrier alone orders "phase-k reads of rows R" before
//    "phase-k+1 DMA stages into rows R". Hazard trace per phase below.
//  * Fuse the two prep kernels into one dispatch.

#define T_DIM 8192
#define M_DIM 4096
#define N_DIM 4096
#define RANK  8

typedef _Float16 f16x8 __attribute__((ext_vector_type(8)));
typedef float    f32x4 __attribute__((ext_vector_type(4)));

// ---------------------------------------------------------------- prep
// blocks [0, 16384): Xh = f16(x)            (pure streaming cast)
// blocks [16384, 24576): Wh = f16(W + A@B^T) (delta_W folded into W)
#define CAST_BLOCKS 16384
__global__ __launch_bounds__(256)
void prep_all(const float* __restrict__ x, const float* __restrict__ W,
              const float* __restrict__ A, const float* __restrict__ B,
              _Float16* __restrict__ Xh, _Float16* __restrict__ Wh) {
    const int bid = blockIdx.x;
    if (bid < CAST_BLOCKS) {
        size_t i = ((size_t)bid * 256 + threadIdx.x) * 8;
        f32x4 v0 = *(const f32x4*)(x + i);
        f32x4 v1 = *(const f32x4*)(x + i + 4);
        f16x8 o;
#pragma unroll
        for (int k = 0; k < 4; ++k) { o[k] = (_Float16)v0[k]; o[4 + k] = (_Float16)v1[k]; }
        *(f16x8*)(Xh + i) = o;
    } else {
        const size_t c = (size_t)(bid - CAST_BLOCKS) * 256 + threadIdx.x;
        const int m  = (int)(c >> 9);
        const int n0 = (int)(c & 511) << 3;
        f32x4 a0 = *(const f32x4*)(A + (size_t)m * RANK);
        f32x4 a1 = *(const f32x4*)(A + (size_t)m * RANK + 4);
        const float* wp = W + (size_t)m * N_DIM + n0;
        f32x4 w0 = *(const f32x4*)wp;
        f32x4 w1 = *(const f32x4*)(wp + 4);
        f16x8 o;
#pragma unroll
        for (int k = 0; k < 8; ++k) {
            const float* Bn = B + (size_t)(n0 + k) * RANK;
            f32x4 b0 = *(const f32x4*)Bn;
            f32x4 b1 = *(const f32x4*)(Bn + 4);
            float d = a0[0]*b0[0] + a0[1]*b0[1] + a0[2]*b0[2] + a0[3]*b0[3]
                    + a1[0]*b1[0] + a1[1]*b1[1] + a1[2]*b1[2] + a1[3]*b1[3];
            float wv = (k < 4) ? w0[k] : w1[k - 4];
            o[k] = (_Float16)(wv + d);
        }
        *(f16x8*)(Wh + (size_t)m * N_DIM + n0) = o;
    }
}

// ---------------------------------------------------------------- GEMM
__device__ static inline void gld16(const _Float16* g, _Float16* l) {
    __builtin_amdgcn_global_load_lds(
        (const __attribute__((address_space(1))) unsigned int*)g,
        (__attribute__((address_space(3))) unsigned int*)l, 16, 0, 0);
}

// 256x256 tile, BK=64, 512 threads = 8 waves (2M x 4N), per-wave C = 128x64.
// LDS: double-buffered [256][64] f16 tiles for A and B = 128 KiB.
// 16B chunk c of row R stored at phys chunk c ^ (R&7) (involution; staged
// via pre-swizzled global source so global_load_lds' linear dest works).
// B rows permuted: phys p = nb*128 + wcn*32 + s <-> W row wcn*64 + nb*32 + s.
__global__ __launch_bounds__(512, 2)
void gemm256(const _Float16* __restrict__ Xh, const _Float16* __restrict__ Wh,
             const float* __restrict__ bias, float* __restrict__ out) {
    __shared__ __align__(16) _Float16 lA[2][256 * 64];
    __shared__ __align__(16) _Float16 lB[2][256 * 64];

    const int tid  = threadIdx.x;
    const int lane = tid & 63;
    const int fr   = lane & 15;
    const int fq   = lane >> 4;
    const int w    = tid >> 6;
    const int wr   = w >> 2;      // 0..1  (M)
    const int wcn  = w & 3;       // 0..3  (N)

    const size_t rowX0 = (size_t)blockIdx.y * 256;
    const size_t rowW0 = (size_t)blockIdx.x * 256;

    // staging source addressing (per-thread, kt-invariant)
    const int srow = tid >> 3;                                // 0..63
    const int scol = ((tid & 7) * 8) ^ ((srow & 7) * 8);      // pre-swizzled col
    const _Float16* sA = Xh + (rowX0 + srow) * N_DIM + scol;
    const _Float16* sBp[4];
#pragma unroll
    for (int cb = 0; cb < 4; ++cb) {
        const int p = cb * 64 + srow;
        const int wrow = ((p >> 5) & 3) * 64 + ((p >> 7) & 1) * 32 + (p & 31);
        sBp[cb] = Wh + (rowW0 + wrow) * N_DIM + scol;
    }

    // fragment-read swizzled column (f16 units); ksub=1 flips bit 5
    const int kc0 = (fq * 8) ^ ((fr & 7) * 8);

    f32x4 acc[8][4] = {};
    f16x8 af[4][2], bf[4][2];

#define STAGE_A(b, rb, kt) gld16(sA + (size_t)(rb) * N_DIM + (kt) * 64, \
                                 &lA[b][(rb) * 64 + tid * 8])
#define STAGE_B(b, cb, kt) gld16(sBp[cb] + (size_t)(kt) * 64, \
                                 &lB[b][(cb) * 4096 + tid * 8])

#define LDA(b, qm) do { _Pragma("unroll") \
    for (int ii = 0; ii < 4; ++ii) { \
        const int ro_ = (wr * 128 + (qm) * 64 + ii * 16 + fr) * 64; \
        af[ii][0] = *(const f16x8*)&lA[b][ro_ + kc0]; \
        af[ii][1] = *(const f16x8*)&lA[b][ro_ + (kc0 ^ 32)]; } } while (0)

#define LDB(b, qn) do { _Pragma("unroll") \
    for (int jj = 0; jj < 2; ++jj) { \
        const int ro_ = ((qn) * 128 + wcn * 32 + jj * 16 + fr) * 64; \
        bf[(qn) * 2 + jj][0] = *(const f16x8*)&lB[b][ro_ + kc0]; \
        bf[(qn) * 2 + jj][1] = *(const f16x8*)&lB[b][ro_ + (kc0 ^ 32)]; } } while (0)

#define MMA(qm, qn) do { __builtin_amdgcn_s_setprio(1); \
    _Pragma("unroll") for (int ii = 0; ii < 4; ++ii) \
    _Pragma("unroll") for (int jj = 0; jj < 2; ++jj) { \
        acc[(qm)*4+ii][(qn)*2+jj] = __builtin_amdgcn_mfma_f32_16x16x32_f16( \
            af[ii][0], bf[(qn)*2+jj][0], acc[(qm)*4+ii][(qn)*2+jj], 0, 0, 0); \
        acc[(qm)*4+ii][(qn)*2+jj] = __builtin_amdgcn_mfma_f32_16x16x32_f16( \
            af[ii][1], bf[(qn)*2+jj][1], acc[(qm)*4+ii][(qn)*2+jj], 0, 0, 0); } \
    __builtin_amdgcn_s_setprio(0); \
    __builtin_amdgcn_sched_barrier(0); } while (0)

#define BAR asm volatile("s_barrier" ::: "memory")
#define VW4 asm volatile("s_waitcnt vmcnt(4)" ::: "memory")
#define VW0 asm volatile("s_waitcnt vmcnt(0)" ::: "memory")

    // ---- prologue: kt0 full -> buf0 (8); kt1 A-q0 + B-h0 -> buf1 (4)
    STAGE_A(0, 0, 0);  STAGE_A(0, 64, 0);  STAGE_A(0, 128, 0);  STAGE_A(0, 192, 0);
    STAGE_B(0, 0, 0);  STAGE_B(0, 1, 0);   STAGE_B(0, 2, 0);    STAGE_B(0, 3, 0);
    STAGE_A(1, 0, 1);  STAGE_A(1, 128, 1); STAGE_B(1, 0, 1);    STAGE_B(1, 1, 1);
    VW4; BAR;   // kt0 confirmed; kt1-first(4) outstanding

    // ---- main loop: iter n computes kt 2n (buf0), 2n+1 (buf1)
    // Hazard trace (rows staged vs last read):
    //  PhA stages buf1 A{64-127,192-255}+B{128-255}: last read prev PhD /
    //      prev PhC — >=1 end-barrier ago.  PhA reads buf0 A-q0 + B-all.
    //  PhB stages buf0 A{0-63,128-191}+B{0-127}: last read PhA (its barrier
    //      intervenes).  PhB reads buf0 A-q1 (disjoint from its stages).
    //  PhC stages buf0 A{64-127,192-255}+B{128-255}: last read PhB / PhA.
    //      PhC reads buf1 (disjoint buffer).  Buf1 staging confirmed by
    //      PhB's VW4+BAR (PhA's 4 stages are among the 8 oldest).
    //  PhD stages buf1 A{0-63,128-191}+B{0-127}: last read PhC.  PhD reads
    //      buf1 A-q1 (disjoint).  Buf0 kt+2 confirmed by PhD's VW4+BAR.
#pragma unroll 1
    for (int n = 0; n < 31; ++n) {
        const int ko  = 2 * n + 1;
        const int ke2 = 2 * n + 2;
        const int ko2 = 2 * n + 3;
        // PhA
        STAGE_A(1, 64, ko); STAGE_A(1, 192, ko); STAGE_B(1, 2, ko); STAGE_B(1, 3, ko);
        LDA(0, 0); LDB(0, 0); LDB(0, 1);
        MMA(0, 0); MMA(0, 1);
        BAR;
        // PhB
        STAGE_A(0, 0, ke2); STAGE_A(0, 128, ke2); STAGE_B(0, 0, ke2); STAGE_B(0, 1, ke2);
        LDA(0, 1);
        MMA(1, 0); MMA(1, 1);
        VW4; BAR;   // kt_odd fully staged (globally, via barrier)
        // PhC
        STAGE_A(0, 64, ke2); STAGE_A(0, 192, ke2); STAGE_B(0, 2, ke2); STAGE_B(0, 3, ke2);
        LDA(1, 0); LDB(1, 0); LDB(1, 1);
        MMA(0, 0); MMA(0, 1);
        BAR;
        // PhD
        STAGE_A(1, 0, ko2); STAGE_A(1, 128, ko2); STAGE_B(1, 0, ko2); STAGE_B(1, 1, ko2);
        LDA(1, 1);
        MMA(1, 0); MMA(1, 1);
        VW4; BAR;   // kt_even+2 fully staged
    }

    // ---- final: kt62 (buf0), kt63 (buf1); no further prefetch
    STAGE_A(1, 64, 63); STAGE_A(1, 192, 63); STAGE_B(1, 2, 63); STAGE_B(1, 3, 63);
    LDA(0, 0); LDB(0, 0); LDB(0, 1);
    MMA(0, 0); MMA(0, 1);
    BAR;
    LDA(0, 1);
    MMA(1, 0); MMA(1, 1);
    VW0; BAR;           // kt63 staging globally complete
    LDA(1, 0); LDB(1, 0); LDB(1, 1);
    MMA(0, 0); MMA(0, 1);
    LDA(1, 1);
    MMA(1, 0); MMA(1, 1);

    // ---- epilogue: C/D col = lane&15 (out col m), row = (lane>>4)*4 + reg
    const int crow0 = (int)rowX0 + wr * 64;
    const int ccol0 = (int)rowW0 + wcn * 64;
    (void)crow0; (void)ccol0;
    {
        const int crow = (int)rowX0 + wr * 128;
        const int ccol = (int)rowW0 + wcn * 64;
        float bv[4];
#pragma unroll
        for (int j = 0; j < 4; ++j) bv[j] = bias[ccol + j * 16 + fr];
#pragma unroll
        for (int i = 0; i < 8; ++i) {
#pragma unroll
            for (int r = 0; r < 4; ++r) {
                const size_t row = (size_t)(crow + i * 16 + fq * 4 + r);
#pragma unroll
                for (int j = 0; j < 4; ++j)
                    out[row * M_DIM + ccol + j * 16 + fr] = acc[i][j][r] + bv[j];
            }
        }
    }
#undef STAGE_A
#undef STAGE_B
#undef LDA
#undef LDB
#undef MMA
#undef BAR
#undef VW4
#undef VW0
}

// ---------------------------------------------------------------- launch
extern "C" void kernel_launch(void* const* d_in, const int* in_sizes, int n_in,
                              void* d_out, int out_size, void* d_ws, size_t ws_size,
                              hipStream_t stream) {
    const float* x = (const float*)d_in[0];
    const float* W = (const float*)d_in[1];
    const float* b = (const float*)d_in[2];
    const float* A = (const float*)d_in[3];
    const float* B = (const float*)d_in[4];
    float* out = (float*)d_out;

    _Float16* Wh = (_Float16*)d_ws;
    _Float16* Xh = (_Float16*)((char*)d_ws + (size_t)M_DIM * N_DIM * 2);

    prep_all<<<CAST_BLOCKS + (M_DIM * N_DIM / 8) / 256, 256, 0, stream>>>(
        x, W, A, B, Xh, Wh);

    dim3 grid(M_DIM / 256, T_DIM / 256);
    gemm256<<<grid, dim3(512, 1, 1), 0, stream>>>(Xh, Wh, b, out);
}

// Round 4
// 556.530 us; speedup vs baseline: 1.0847x; 1.0337x over previous
//
#include <hip/hip_runtime.h>
#include <cstdint>
#include <cstddef>

// LoRALinear: out[T,M] = x[T,N] @ (W + A@B^T)^T + b   (alpha = 8/8 = 1)
// T=8192, M=4096, N=4096, RANK=8, fp32 in/out.
//
// Round-7 = round-4 schedule (best measured: 270us GEMM) + m201-template
// fidelity fixes:
//  * 8 phases/iter, TWO barriers per phase (pre-MMA + post-MMA) — the
//    round-6 single-barrier merge measurably regressed, so restored.
//  * Even staging: exactly 2 global_load_lds per phase (1 half-tile).
//  * vmcnt(6) (= 2 loads x 3 half-tiles in flight) at ph3/ph7 end only.
//  * ds_reads issued BEFORE stage-issues in each phase; explicit
//    s_waitcnt lgkmcnt(0) after the pre-MMA barrier.
//  * Fused prep (Xh cast + Wh=f16(W+A@B^T) fold) in one dispatch.

#define T_DIM 8192
#define M_DIM 4096
#define N_DIM 4096
#define RANK  8

typedef _Float16 f16x8 __attribute__((ext_vector_type(8)));
typedef float    f32x4 __attribute__((ext_vector_type(4)));

// ---------------------------------------------------------------- prep
#define CAST_BLOCKS 16384
__global__ __launch_bounds__(256)
void prep_all(const float* __restrict__ x, const float* __restrict__ W,
              const float* __restrict__ A, const float* __restrict__ B,
              _Float16* __restrict__ Xh, _Float16* __restrict__ Wh) {
    const int bid = blockIdx.x;
    if (bid < CAST_BLOCKS) {
        size_t i = ((size_t)bid * 256 + threadIdx.x) * 8;
        f32x4 v0 = *(const f32x4*)(x + i);
        f32x4 v1 = *(const f32x4*)(x + i + 4);
        f16x8 o;
#pragma unroll
        for (int k = 0; k < 4; ++k) { o[k] = (_Float16)v0[k]; o[4 + k] = (_Float16)v1[k]; }
        *(f16x8*)(Xh + i) = o;
    } else {
        const size_t c = (size_t)(bid - CAST_BLOCKS) * 256 + threadIdx.x;
        const int m  = (int)(c >> 9);
        const int n0 = (int)(c & 511) << 3;
        f32x4 a0 = *(const f32x4*)(A + (size_t)m * RANK);
        f32x4 a1 = *(const f32x4*)(A + (size_t)m * RANK + 4);
        const float* wp = W + (size_t)m * N_DIM + n0;
        f32x4 w0 = *(const f32x4*)wp;
        f32x4 w1 = *(const f32x4*)(wp + 4);
        f16x8 o;
#pragma unroll
        for (int k = 0; k < 8; ++k) {
            const float* Bn = B + (size_t)(n0 + k) * RANK;
            f32x4 b0 = *(const f32x4*)Bn;
            f32x4 b1 = *(const f32x4*)(Bn + 4);
            float d = a0[0]*b0[0] + a0[1]*b0[1] + a0[2]*b0[2] + a0[3]*b0[3]
                    + a1[0]*b1[0] + a1[1]*b1[1] + a1[2]*b1[2] + a1[3]*b1[3];
            float wv = (k < 4) ? w0[k] : w1[k - 4];
            o[k] = (_Float16)(wv + d);
        }
        *(f16x8*)(Wh + (size_t)m * N_DIM + n0) = o;
    }
}

// ---------------------------------------------------------------- GEMM
__device__ static inline void gld16(const _Float16* g, _Float16* l) {
    __builtin_amdgcn_global_load_lds(
        (const __attribute__((address_space(1))) unsigned int*)g,
        (__attribute__((address_space(3))) unsigned int*)l, 16, 0, 0);
}

// 256x256 tile, BK=64, 512 threads = 8 waves (2M x 4N), per-wave C = 128x64.
// LDS: double-buffered [256][64] f16 tiles for A and B = 128 KiB.
// 16B chunk c of row R stored at phys chunk c ^ (R&7) (involution; staged
// via pre-swizzled global source so global_load_lds' linear dest works).
// B rows permuted: phys p = qn*128 + wcn*32 + jj*16 + fr <-> W row
// wcn*64 + qn*32 + jj*16 + fr.
//
// Stage units (2 glds each): Aq0 = A rows {0-63,128-191}, Aq1 = {64-127,
// 192-255}, Bh0 = B phys {0-127}, Bh1 = B phys {128-255}.
// Reads per K-tile: ph+0: Aq0,Bh0 · ph+1: Bh1 · ph+2: Aq1 · ph+3: none.
//
// Steady-state stage map (2 glds EVERY phase; WAR: target's last read
// drained >=1 end-barrier earlier; RAW: unit confirmed by a VW6+BAR
// before first read):
//   ph0: buf1.Bh1(ko)   [last read prev ph5]
//   ph1: buf0.Aq0(ke2)  [last read ph0]
//   ph2: buf0.Bh0(ke2)  [last read ph0]
//   ph3: buf0.Bh1(ke2)  [last read ph1]   + VW6 -> confirms kt_odd
//   ph4: buf0.Aq1(ke2)  [last read ph2]
//   ph5: buf1.Aq0(ko2)  [last read ph4]
//   ph6: buf1.Bh0(ko2)  [last read ph4]
//   ph7: buf1.Aq1(ko2)  [last read ph6]   + VW6 -> confirms kt_even+2
// VW6 accounting: at ph3 outstanding = {ph5,6,7 prev}+{ph0..3} = 14;
// wait->6 confirms through ph0 (kt_odd complete). Symmetric at ph7.
__global__ __launch_bounds__(512, 2)
void gemm256(const _Float16* __restrict__ Xh, const _Float16* __restrict__ Wh,
             const float* __restrict__ bias, float* __restrict__ out) {
    __shared__ __align__(16) _Float16 lA[2][256 * 64];
    __shared__ __align__(16) _Float16 lB[2][256 * 64];

    const int tid  = threadIdx.x;
    const int lane = tid & 63;
    const int fr   = lane & 15;
    const int fq   = lane >> 4;
    const int w    = tid >> 6;
    const int wr   = w >> 2;      // 0..1  (M)
    const int wcn  = w & 3;       // 0..3  (N)

    const size_t rowX0 = (size_t)blockIdx.y * 256;
    const size_t rowW0 = (size_t)blockIdx.x * 256;

    // staging source addressing (per-thread, kt-invariant)
    const int srow = tid >> 3;                                // 0..63
    const int scol = ((tid & 7) * 8) ^ ((srow & 7) * 8);      // pre-swizzled col
    const _Float16* sA = Xh + (rowX0 + srow) * N_DIM + scol;
    const _Float16* sBp[4];
#pragma unroll
    for (int cb = 0; cb < 4; ++cb) {
        const int p = cb * 64 + srow;
        const int wrow = ((p >> 5) & 3) * 64 + ((p >> 7) & 1) * 32 + (p & 31);
        sBp[cb] = Wh + (rowW0 + wrow) * N_DIM + scol;
    }

    // fragment-read swizzled column (f16 units); ksub=1 flips bit 5
    const int kc0 = (fq * 8) ^ ((fr & 7) * 8);

    f32x4 acc[8][4] = {};
    f16x8 af[4][2], bf[4][2];

#define STAGE_A(b, rb, kt) gld16(sA + (size_t)(rb) * N_DIM + (kt) * 64, \
                                 &lA[b][(rb) * 64 + tid * 8])
#define STAGE_B(b, cb, kt) gld16(sBp[cb] + (size_t)(kt) * 64, \
                                 &lB[b][(cb) * 4096 + tid * 8])

#define LDA(b, qm) do { _Pragma("unroll") \
    for (int ii = 0; ii < 4; ++ii) { \
        const int ro_ = (wr * 128 + (qm) * 64 + ii * 16 + fr) * 64; \
        af[ii][0] = *(const f16x8*)&lA[b][ro_ + kc0]; \
        af[ii][1] = *(const f16x8*)&lA[b][ro_ + (kc0 ^ 32)]; } } while (0)

#define LDB(b, qn) do { _Pragma("unroll") \
    for (int jj = 0; jj < 2; ++jj) { \
        const int ro_ = ((qn) * 128 + wcn * 32 + jj * 16 + fr) * 64; \
        bf[(qn) * 2 + jj][0] = *(const f16x8*)&lB[b][ro_ + kc0]; \
        bf[(qn) * 2 + jj][1] = *(const f16x8*)&lB[b][ro_ + (kc0 ^ 32)]; } } while (0)

// phase tail: pre-MMA barrier, lgkm drain (free: reads had the barrier
// wait to complete), prioritized MFMA cluster, post-MMA barrier.
#define MMA(qm, qn) do { \
    asm volatile("s_barrier" ::: "memory"); \
    asm volatile("s_waitcnt lgkmcnt(0)" ::: "memory"); \
    __builtin_amdgcn_s_setprio(1); \
    _Pragma("unroll") for (int ii = 0; ii < 4; ++ii) \
    _Pragma("unroll") for (int jj = 0; jj < 2; ++jj) { \
        acc[(qm)*4+ii][(qn)*2+jj] = __builtin_amdgcn_mfma_f32_16x16x32_f16( \
            af[ii][0], bf[(qn)*2+jj][0], acc[(qm)*4+ii][(qn)*2+jj], 0, 0, 0); \
        acc[(qm)*4+ii][(qn)*2+jj] = __builtin_amdgcn_mfma_f32_16x16x32_f16( \
            af[ii][1], bf[(qn)*2+jj][1], acc[(qm)*4+ii][(qn)*2+jj], 0, 0, 0); } \
    __builtin_amdgcn_s_setprio(0); \
    __builtin_amdgcn_sched_barrier(0); } while (0)

#define BAR asm volatile("s_barrier" ::: "memory")
#define VW6 asm volatile("s_waitcnt vmcnt(6)" ::: "memory")
#define VW0 asm volatile("s_waitcnt vmcnt(0)" ::: "memory")

    // ---- prologue: kt0 all 8; kt1 Aq0, Bh0, Aq1 (6) -> steady-state shape
    STAGE_A(0, 0, 0);  STAGE_A(0, 64, 0);  STAGE_A(0, 128, 0);  STAGE_A(0, 192, 0);
    STAGE_B(0, 0, 0);  STAGE_B(0, 1, 0);   STAGE_B(0, 2, 0);    STAGE_B(0, 3, 0);
    STAGE_A(1, 0, 1);  STAGE_A(1, 128, 1);                      // kt1.Aq0
    STAGE_B(1, 0, 1);  STAGE_B(1, 1, 1);                        // kt1.Bh0
    STAGE_A(1, 64, 1); STAGE_A(1, 192, 1);                      // kt1.Aq1
    VW6; BAR;   // kt0 confirmed; kt1 minus Bh1 outstanding (6)

    // ---- main loop: iter n computes kt 2n (buf0), 2n+1 (buf1)
#pragma unroll 1
    for (int n = 0; n < 31; ++n) {
        const int ko  = 2 * n + 1;
        const int ke2 = 2 * n + 2;
        const int ko2 = 2 * n + 3;
        // ph0
        LDA(0, 0); LDB(0, 0);
        STAGE_B(1, 2, ko); STAGE_B(1, 3, ko);
        MMA(0, 0); BAR;
        // ph1
        LDB(0, 1);
        STAGE_A(0, 0, ke2); STAGE_A(0, 128, ke2);
        MMA(0, 1); BAR;
        // ph2
        LDA(0, 1);
        STAGE_B(0, 0, ke2); STAGE_B(0, 1, ke2);
        MMA(1, 0); BAR;
        // ph3
        STAGE_B(0, 2, ke2); STAGE_B(0, 3, ke2);
        MMA(1, 1); VW6; BAR;   // kt_odd fully staged (global via barrier)
        // ph4
        LDA(1, 0); LDB(1, 0);
        STAGE_A(0, 64, ke2); STAGE_A(0, 192, ke2);
        MMA(0, 0); BAR;
        // ph5
        LDB(1, 1);
        STAGE_A(1, 0, ko2); STAGE_A(1, 128, ko2);
        MMA(0, 1); BAR;
        // ph6
        LDA(1, 1);
        STAGE_B(1, 0, ko2); STAGE_B(1, 1, ko2);
        MMA(1, 0); BAR;
        // ph7
        STAGE_A(1, 64, ko2); STAGE_A(1, 192, ko2);
        MMA(1, 1); VW6; BAR;   // kt_even+2 fully staged
    }

    // ---- final: kt62 (buf0), kt63 (buf1); only kt63.Bh1 left to stage
    LDA(0, 0); LDB(0, 0);
    STAGE_B(1, 2, 63); STAGE_B(1, 3, 63);
    MMA(0, 0); BAR;
    LDB(0, 1);
    MMA(0, 1); BAR;
    LDA(0, 1);
    MMA(1, 0); BAR;
    MMA(1, 1); VW0; BAR;       // kt63 staging globally complete
    LDA(1, 0); LDB(1, 0);
    MMA(0, 0); BAR;
    LDB(1, 1);
    MMA(0, 1); BAR;
    LDA(1, 1);
    MMA(1, 0); BAR;
    MMA(1, 1);

    // ---- epilogue: C/D col = lane&15 (out col m), row = (lane>>4)*4 + reg
    {
        const int crow = (int)rowX0 + wr * 128;
        const int ccol = (int)rowW0 + wcn * 64;
        float bv[4];
#pragma unroll
        for (int j = 0; j < 4; ++j) bv[j] = bias[ccol + j * 16 + fr];
#pragma unroll
        for (int i = 0; i < 8; ++i) {
#pragma unroll
            for (int r = 0; r < 4; ++r) {
                const size_t row = (size_t)(crow + i * 16 + fq * 4 + r);
#pragma unroll
                for (int j = 0; j < 4; ++j)
                    out[row * M_DIM + ccol + j * 16 + fr] = acc[i][j][r] + bv[j];
            }
        }
    }
#undef STAGE_A
#undef STAGE_B
#undef LDA
#undef LDB
#undef MMA
#undef BAR
#undef VW6
#undef VW0
}

// ---------------------------------------------------------------- launch
extern "C" void kernel_launch(void* const* d_in, const int* in_sizes, int n_in,
                              void* d_out, int out_size, void* d_ws, size_t ws_size,
                              hipStream_t stream) {
    const float* x = (const float*)d_in[0];
    const float* W = (const float*)d_in[1];
    const float* b = (const float*)d_in[2];
    const float* A = (const float*)d_in[3];
    const float* B = (const float*)d_in[4];
    float* out = (float*)d_out;

    _Float16* Wh = (_Float16*)d_ws;
    _Float16* Xh = (_Float16*)((char*)d_ws + (size_t)M_DIM * N_DIM * 2);

    prep_all<<<CAST_BLOCKS + (M_DIM * N_DIM / 8) / 256, 256, 0, stream>>>(
        x, W, A, B, Xh, Wh);

    dim3 grid(M_DIM / 256, T_DIM / 256);
    gemm256<<<grid, dim3(512, 1, 1), 0, stream>>>(Xh, Wh, b, out);
}